// Round 7
// baseline (2656.611 us; speedup 1.0000x reference)
//
#include <hip/hip_runtime.h>
#include <hip/hip_bf16.h>
#include <hip/hip_fp16.h>
#include <math.h>

#define N_NODES 65536
#define N_EDGES 1048576
#define NB      32
#define D       64
#define NLAYERS 4
#define G       16     // dst nodes per edge-block
#define CH      64     // edges per chunk
#define AST     76     // ushort stride, edge-kernel activation planes
#define PST     68     // ushort stride, p / M f16 planes
#define NST     72     // ushort stride, nodegemm planes
#define LOOFS   24576  // ushort offset of lo-plane in packed weights (per layer)
#define LSTRIDE 49152  // ushort stride per layer in packed weights

typedef __attribute__((ext_vector_type(8))) short short8;   // 8 bf16 in 4 VGPRs
typedef __attribute__((ext_vector_type(4))) float f32x4;

__device__ __forceinline__ float relu_f(float x){ return x > 0.f ? x : 0.f; }
__device__ __forceinline__ unsigned short bfbits(float x){
    __bf16 h = (__bf16)x;
    return __builtin_bit_cast(unsigned short, h);
}
__device__ __forceinline__ float bfval(float x){
    __bf16 h = (__bf16)x;
    return (float)h;
}
__device__ __forceinline__ f32x4 mfma16(short8 a, short8 b, f32x4 c){
    return __builtin_amdgcn_mfma_f32_16x16x32_bf16(a, b, c, 0, 0, 0);
}

// ---------------- sort-by-dst machinery ----------------

__global__ void k_zero(int* __restrict__ p){
    p[blockIdx.x * 256 + threadIdx.x] = 0;
}

__global__ void k_hist(const int* __restrict__ dst, int* __restrict__ deg){
    int e = blockIdx.x * 256 + threadIdx.x;
    if (e < N_EDGES) atomicAdd(&deg[dst[e]], 1);
}

__global__ void k_scan1(const int* __restrict__ deg, int* __restrict__ part, int* __restrict__ bsum){
    __shared__ int s[256];
    int t = threadIdx.x;
    int i = blockIdx.x * 256 + t;
    int v = deg[i];
    s[t] = v; __syncthreads();
    for (int ofs = 1; ofs < 256; ofs <<= 1){
        int tv = (t >= ofs) ? s[t - ofs] : 0;
        __syncthreads();
        s[t] += tv;
        __syncthreads();
    }
    part[i] = s[t] - v;
    if (t == 255) bsum[blockIdx.x] = s[255];
}

__global__ void k_scan2(const int* __restrict__ bsum, int* __restrict__ bofs){
    __shared__ int s[256];
    int t = threadIdx.x;
    int v = bsum[t];
    s[t] = v; __syncthreads();
    for (int ofs = 1; ofs < 256; ofs <<= 1){
        int tv = (t >= ofs) ? s[t - ofs] : 0;
        __syncthreads();
        s[t] += tv;
        __syncthreads();
    }
    bofs[t] = s[t] - v;
}

__global__ void k_scan3(const int* __restrict__ part, const int* __restrict__ bofs,
                        int* __restrict__ off, int* __restrict__ cursor){
    int i = blockIdx.x * 256 + threadIdx.x;
    int o = part[i] + bofs[i >> 8];
    off[i] = o; cursor[i] = o;
    if (i == 0) off[N_NODES] = N_EDGES;
}

__global__ void k_scatter(const int* __restrict__ ei, const float* __restrict__ pos,
                          int* __restrict__ cursor, int* __restrict__ srcs,
                          float* __restrict__ pdb){
    int e = blockIdx.x * 256 + threadIdx.x;
    if (e >= N_EDGES) return;
    int s = ei[e], d = ei[N_EDGES + e];
    int p = atomicAdd(&cursor[d], 1);
    srcs[p]    = s;
    pdb[2*p]   = pos[2*d]   - pos[2*s];
    pdb[2*p+1] = pos[2*d+1] - pos[2*s+1];
}

// ---------------- weight pre-pack into MFMA B-fragment order (hi/lo) ----------------
// 6 matrices per layer: 0..2 = pW2,aW1,aW2 (edge kernel), 3..5 = Wl,Ws,Wd (node GEMM).
// Per layer: hi plane 24576 ushorts at [mat][nb][kf][lane][8], lo plane at +LOOFS.
// B-frag: lane holds B[k = kf*32 + (lane>>4)*8 + j][n = nb*16 + (lane&15)], j=0..7.

__global__ void k_pack(const float* __restrict__ pW2, const float* __restrict__ aW1,
                       const float* __restrict__ aW2, const float* __restrict__ Wl,
                       const float* __restrict__ Ws, const float* __restrict__ Wd,
                       unsigned short* __restrict__ bpk){
    int b  = blockIdx.x;                // L*48 + mat*8 + nb*2 + kf
    int kf = b & 1, nb = (b >> 1) & 3;
    int mat = (b >> 3) % 6, L = b / 48;
    int t = threadIdx.x;
    int lane = t & 63, jj = (t >> 6) * 2;
    const float* Wsel[6] = {pW2, aW1, aW2, Wl, Ws, Wd};
    const float* W = Wsel[mat] + (size_t)L * D * D;
    int n = nb * 16 + (lane & 15);
    unsigned short* dsthi = bpk + (size_t)L * LSTRIDE
                          + (((size_t)mat * 4 + nb) * 2 + kf) * 512 + lane * 8 + jj;
    #pragma unroll
    for (int u = 0; u < 2; ++u){
        int j = jj + u;
        int k = kf * 32 + (lane >> 4) * 8 + j;
        float w = W[k * D + n];
        float hv = bfval(w);
        dsthi[u]         = bfbits(w);
        dsthi[LOOFS + u] = bfbits(w - hv);
    }
}

// ---------------- nodegemm helper: A hi/lo in LDS, persistent B frags ----------------

__device__ __forceinline__ void gemm_hl(const unsigned short* __restrict__ Ah,
                                        const unsigned short* __restrict__ Al,
                                        const short8* Bh, const short8* Bl,
                                        int ln, int q, f32x4* accs)
{
    #pragma unroll
    for (int mt = 0; mt < 4; ++mt){
        int ro = (mt*16 + ln) * NST;
        short8 ah0 = __builtin_bit_cast(short8, *(const uint4*)(Ah + ro + q*8));
        short8 ah1 = __builtin_bit_cast(short8, *(const uint4*)(Ah + ro + 32 + q*8));
        short8 al0 = __builtin_bit_cast(short8, *(const uint4*)(Al + ro + q*8));
        short8 al1 = __builtin_bit_cast(short8, *(const uint4*)(Al + ro + 32 + q*8));
        f32x4 acc = {0.f, 0.f, 0.f, 0.f};
        acc = mfma16(ah0, Bh[0], acc);
        acc = mfma16(ah1, Bh[1], acc);
        acc = mfma16(al0, Bh[0], acc);
        acc = mfma16(al1, Bh[1], acc);
        acc = mfma16(ah0, Bl[0], acc);
        acc = mfma16(ah1, Bl[1], acc);
        accs[mt] = acc;
    }
}

// ---------------- node GEMM (MFMA): va (packed half2 v|as) and ad (fp32) ----------------

__global__ __launch_bounds__(256, 4) void k_nodegemm(
    const float* __restrict__ h, const unsigned short* __restrict__ bpkL,
    unsigned int* __restrict__ VA, float* __restrict__ ad)
{
    __shared__ __align__(16) unsigned short Hhi[64 * NST];
    __shared__ __align__(16) unsigned short Hlo[64 * NST];
    int row0 = blockIdx.x * 64;
    int t = threadIdx.x;
    {
        int r  = t >> 2;
        int kb = (t & 3) * 16;
        const float4* hp = (const float4*)(h + (size_t)(row0 + r) * D + kb);
        unsigned int hw[8], lw[8];
        #pragma unroll
        for (int i4 = 0; i4 < 4; ++i4){
            float4 a = hp[i4];
            float f[4] = {a.x, a.y, a.z, a.w};
            #pragma unroll
            for (int p = 0; p < 2; ++p){
                float f0 = f[p*2], f1 = f[p*2+1];
                unsigned short h0 = bfbits(f0), h1 = bfbits(f1);
                unsigned short l0 = bfbits(f0 - bfval(f0)), l1 = bfbits(f1 - bfval(f1));
                hw[i4*2 + p] = (unsigned int)h0 | ((unsigned int)h1 << 16);
                lw[i4*2 + p] = (unsigned int)l0 | ((unsigned int)l1 << 16);
            }
        }
        *(uint4*)&Hhi[r*NST + kb]     = make_uint4(hw[0], hw[1], hw[2], hw[3]);
        *(uint4*)&Hhi[r*NST + kb + 8] = make_uint4(hw[4], hw[5], hw[6], hw[7]);
        *(uint4*)&Hlo[r*NST + kb]     = make_uint4(lw[0], lw[1], lw[2], lw[3]);
        *(uint4*)&Hlo[r*NST + kb + 8] = make_uint4(lw[4], lw[5], lw[6], lw[7]);
    }
    __syncthreads();
    int w = t >> 6, lane = t & 63;
    int q = lane >> 4, ln = lane & 15;
    int c = w * 16 + ln;
    short8 Bh[3][2], Bl[3][2];
    #pragma unroll
    for (int g = 0; g < 3; ++g)
        #pragma unroll
        for (int kf = 0; kf < 2; ++kf){
            int idx = (((g + 3)*4 + w)*2 + kf)*512 + lane*8;
            Bh[g][kf] = __builtin_bit_cast(short8, *(const uint4*)(bpkL + idx));
            Bl[g][kf] = __builtin_bit_cast(short8, *(const uint4*)(bpkL + LOOFS + idx));
        }
    f32x4 accs[4];
    float vres[16];
    gemm_hl(Hhi, Hlo, Bh[0], Bl[0], ln, q, accs);   // Wl -> v
    #pragma unroll
    for (int mt = 0; mt < 4; ++mt)
        #pragma unroll
        for (int r = 0; r < 4; ++r)
            vres[mt*4 + r] = accs[mt][r];
    gemm_hl(Hhi, Hlo, Bh[1], Bl[1], ln, q, accs);   // Ws -> as; pack (v, as) half2
    #pragma unroll
    for (int mt = 0; mt < 4; ++mt)
        #pragma unroll
        for (int r = 0; r < 4; ++r){
            __half2 pk = __halves2half2(__float2half(vres[mt*4 + r]), __float2half(accs[mt][r]));
            VA[(size_t)(row0 + mt*16 + q*4 + r) * D + c] = __builtin_bit_cast(unsigned int, pk);
        }
    gemm_hl(Hhi, Hlo, Bh[2], Bl[2], ln, q, accs);   // Wd -> ad (fp32)
    #pragma unroll
    for (int mt = 0; mt < 4; ++mt)
        #pragma unroll
        for (int r = 0; r < 4; ++r)
            ad[(size_t)(row0 + mt*16 + q*4 + r) * D + c] = accs[mt][r];
}

// ---------------- edge-kernel gemm: A single-plane bf16 LDS, B hi/lo persistent ----------------

__device__ __forceinline__ void gemm1p(const unsigned short* __restrict__ A,
                                       const short8* Bh, const short8* Bl,
                                       int ln, int q, f32x4* accs)
{
    #pragma unroll
    for (int mt = 0; mt < 4; ++mt){
        int ro = (mt*16 + ln) * AST;
        short8 a0 = __builtin_bit_cast(short8, *(const uint4*)(A + ro + q*8));
        short8 a1 = __builtin_bit_cast(short8, *(const uint4*)(A + ro + 32 + q*8));
        f32x4 acc = {0.f, 0.f, 0.f, 0.f};
        acc = mfma16(a0, Bh[0], acc);
        acc = mfma16(a1, Bh[1], acc);
        acc = mfma16(a0, Bl[0], acc);
        acc = mfma16(a1, Bl[1], acc);
        accs[mt] = acc;
    }
}

// ---------------- fused edge kernel: zero cross-barrier register state ----------------
// LDS: T plane (t1/t2) | U plane (u; p f16 overlay) | M f16 plane | DN accumulators.
// Stages: AB (meta + pos-MLP -> T) | C (prefetch VA/ad; gemm1 -> delta; M f16 -> Msh; u -> U)
//         | D (gemm2 -> t2 -> T) | E (gemm3 -> alpha; p f16 -> U overlay)
//         | F (per node: DN.den += p, DN.num += p*M, accumulators in LDS).

__global__ __launch_bounds__(256, 4) void k_edge(
    const int* __restrict__ off, const int* __restrict__ srcs, const float* __restrict__ pdb,
    const unsigned int* __restrict__ VA, const float* __restrict__ adF,
    const float* __restrict__ pW1, const float* __restrict__ pb1, const float* __restrict__ pb2,
    const float* __restrict__ ab1, const float* __restrict__ ab2,
    const unsigned short* __restrict__ bpkL,
    float* __restrict__ hout)
{
    __shared__ __align__(16) unsigned short Tsh[64 * AST];   // 9728 B
    __shared__ __align__(16) unsigned short Ush[64 * AST];   // 9728 B (u; p f16 overlay stride PST)
    __shared__ __align__(16) unsigned short Msh[64 * PST];   // 8704 B (M f16)
    __shared__ float DNsh[256 * 9];                           // 9216 B: den[4] | num[4] | pad
    __shared__ int s_sp[CH];
    __shared__ int s_off[20];
    unsigned short* Ph = Ush;    // p f16 overlay, stride PST

    int t  = threadIdx.x;
    int n0 = blockIdx.x * G;
    if (t <= G) s_off[t] = off[n0 + t];
    #pragma unroll
    for (int i = 0; i < 8; ++i) DNsh[t*9 + i] = 0.f;
    __syncthreads();
    int e_begin = s_off[0], e_end = s_off[G];

    int w = t >> 6, lane = t & 63;
    int q = lane >> 4, ln = lane & 15;
    int c = w * 16 + ln;

    // persistent per-wave B fragments (hi/lo) for mats 0..2 (pW2, aW1, aW2)
    short8 Bh[3][2], Bl[3][2];
    #pragma unroll
    for (int g = 0; g < 3; ++g)
        #pragma unroll
        for (int kf = 0; kf < 2; ++kf){
            int idx = ((g*4 + w)*2 + kf)*512 + lane*8;
            Bh[g][kf] = __builtin_bit_cast(short8, *(const uint4*)(bpkL + idx));
            Bl[g][kf] = __builtin_bit_cast(short8, *(const uint4*)(bpkL + LOOFS + idx));
        }
    float pb2c = pb2[c], ab1c = ab1[c], ab2c = ab2[c];

    for (int ec = e_begin; ec < e_end; ec += CH){
        int cnt = min(CH, e_end - ec);
        // ---- stage AB: edge metadata + t1 = relu(pd @ pW1 + pb1) -> T (bf16)
        {
            int e = t & 63, kb = w * 16;
            int g = ec + ((e < cnt) ? e : 0);
            if (t < CH){
                int s = srcs[g];
                int l = 0;
                while (l < G-1 && g >= s_off[l+1]) ++l;
                s_sp[e] = s | (l << 16);
            }
            float p0 = pdb[2*g], p1 = pdb[2*g+1];
            unsigned int hw[8];
            #pragma unroll
            for (int i2 = 0; i2 < 8; ++i2){
                int k = kb + i2*2;
                float f0 = relu_f(fmaf(p1, pW1[D + k],     fmaf(p0, pW1[k],     pb1[k])));
                float f1 = relu_f(fmaf(p1, pW1[D + k + 1], fmaf(p0, pW1[k + 1], pb1[k + 1])));
                hw[i2] = (unsigned int)bfbits(f0) | ((unsigned int)bfbits(f1) << 16);
            }
            *(uint4*)&Tsh[e*AST + kb]     = make_uint4(hw[0], hw[1], hw[2], hw[3]);
            *(uint4*)&Tsh[e*AST + kb + 8] = make_uint4(hw[4], hw[5], hw[6], hw[7]);
        }
        __syncthreads();
        // ---- stage C: prefetch gathers; gemm1 -> delta; M f16 -> Msh; u bf16 -> U
        {
            unsigned int vaq[16];
            float adq[16];
            #pragma unroll
            for (int i = 0; i < 16; ++i){
                int e = (i >> 2)*16 + q*4 + (i & 3);
                int sp = s_sp[e];
                vaq[i] = VA [(size_t)(sp & 0xFFFF) * D + c];
                adq[i] = adF[(size_t)(n0 + (sp >> 16)) * D + c];
            }
            f32x4 accs[4];
            gemm1p(Tsh, Bh[0], Bl[0], ln, q, accs);
            #pragma unroll
            for (int mt = 0; mt < 4; ++mt){
                #pragma unroll
                for (int r = 0; r < 4; ++r){
                    int i = mt*4 + r;
                    int e = mt*16 + q*4 + r;
                    float dlt = relu_f(accs[mt][r] + pb2c);
                    __half2 va = __builtin_bit_cast(__half2, vaq[i]);
                    float vv = __low2float(va);
                    float vs = __high2float(va);
                    Msh[e*PST + c] = __builtin_bit_cast(unsigned short, __float2half(vv + dlt));
                    Ush[e*AST + c] = bfbits(adq[i] - vs + dlt);
                }
            }
        }
        __syncthreads();
        // ---- stage D: gemm2 (u @ aW1) -> t2 -> T (overwrite t1)
        {
            f32x4 accs[4];
            gemm1p(Ush, Bh[1], Bl[1], ln, q, accs);
            #pragma unroll
            for (int mt = 0; mt < 4; ++mt)
                #pragma unroll
                for (int r = 0; r < 4; ++r){
                    int e = mt*16 + q*4 + r;
                    Tsh[e*AST + c] = bfbits(relu_f(accs[mt][r] + ab1c));
                }
        }
        __syncthreads();
        // ---- stage E: gemm3 (t2 @ aW2) -> alpha; p f16 -> U overlay (u dead after D)
        {
            f32x4 accs[4];
            gemm1p(Tsh, Bh[2], Bl[2], ln, q, accs);
            #pragma unroll
            for (int mt = 0; mt < 4; ++mt){
                #pragma unroll
                for (int r = 0; r < 4; ++r){
                    int e = mt*16 + q*4 + r;
                    float a = relu_f(accs[mt][r] + ab2c);
                    Ph[e*PST + c] = __builtin_bit_cast(unsigned short, __float2half(__expf(a)));
                }
            }
        }
        __syncthreads();
        // ---- stage F: per-node reduction, accumulators in LDS (no cross-barrier regs)
        #pragma unroll
        for (int qn = 0; qn < 4; ++qn){
            int l  = w*4 + qn;
            int gs = max(s_off[l], ec);
            int ge = min(s_off[l+1], ec + cnt);
            float dd = DNsh[t*9 + qn];
            float nn = DNsh[t*9 + 4 + qn];
            for (int g = gs; g < ge; ++g){
                int e = g - ec;
                float p = __half2float(__builtin_bit_cast(__half, Ph[e*PST + lane]));
                float m = __half2float(__builtin_bit_cast(__half, Msh[e*PST + lane]));
                dd += p;
                nn = fmaf(p, m, nn);
            }
            DNsh[t*9 + qn]     = dd;
            DNsh[t*9 + 4 + qn] = nn;
        }
        __syncthreads();
    }
    #pragma unroll
    for (int qn = 0; qn < 4; ++qn){
        int n = n0 + w*4 + qn;
        hout[(size_t)n * D + lane] = DNsh[t*9 + 4 + qn] / DNsh[t*9 + qn];
    }
}

// ---------------- pooling + classifier ----------------

__global__ __launch_bounds__(256) void k_pool(const float* __restrict__ h,
                                              const float* __restrict__ outW,
                                              const float* __restrict__ outb,
                                              float* __restrict__ out)
{
    __shared__ float sm[4][64];
    __shared__ float sp[2][64];
    int b = blockIdx.x;
    int t = threadIdx.x, j = t & 63, g = t >> 6;
    float mx = -1e30f;
    for (int r = b*2048 + g; r < (b+1)*2048; r += 4)
        mx = fmaxf(mx, h[(size_t)r * D + j]);
    sm[g][j] = mx;
    __syncthreads();
    if (t < 64){
        float m = fmaxf(fmaxf(sm[0][j], sm[1][j]), fmaxf(sm[2][j], sm[3][j]));
        sp[0][j] = m * outW[j*2 + 0];
        sp[1][j] = m * outW[j*2 + 1];
    }
    __syncthreads();
    if (t == 0){
        float s0 = outb[0], s1 = outb[1];
        for (int k = 0; k < 64; ++k){ s0 += sp[0][k]; s1 += sp[1][k]; }
        out[b*2]   = s0;
        out[b*2+1] = s1;
    }
}

// ---------------- launch ----------------

extern "C" void kernel_launch(void* const* d_in, const int* in_sizes, int n_in,
                              void* d_out, int out_size, void* d_ws, size_t ws_size,
                              hipStream_t stream)
{
    const float* x    = (const float*)d_in[0];
    const float* pos  = (const float*)d_in[1];
    const float* Wl   = (const float*)d_in[2];
    const float* Ws   = (const float*)d_in[3];
    const float* Wd   = (const float*)d_in[4];
    const float* pW1  = (const float*)d_in[5];
    const float* pb1  = (const float*)d_in[6];
    const float* pW2  = (const float*)d_in[7];
    const float* pb2  = (const float*)d_in[8];
    const float* aW1  = (const float*)d_in[9];
    const float* ab1  = (const float*)d_in[10];
    const float* aW2  = (const float*)d_in[11];
    const float* ab2  = (const float*)d_in[12];
    const float* outW = (const float*)d_in[13];
    const float* outb = (const float*)d_in[14];
    const int*   ei   = (const int*)d_in[15];
    float* out = (float*)d_out;

    char* wp = (char*)d_ws;
    auto alloc = [&](size_t bytes){
        void* p = (void*)wp;
        wp += (bytes + 255) & ~(size_t)255;
        return p;
    };
    int*   deg    = (int*)  alloc((size_t)N_NODES * 4);
    int*   part   = (int*)  alloc((size_t)N_NODES * 4);
    int*   bsum   = (int*)  alloc(1024);
    int*   bofs   = (int*)  alloc(1024);
    int*   off    = (int*)  alloc((size_t)(N_NODES + 1) * 4);
    int*   cursor = (int*)  alloc((size_t)N_NODES * 4);
    int*   srcs   = (int*)  alloc((size_t)N_EDGES * 4);
    float* pdb    = (float*)alloc((size_t)N_EDGES * 8);
    unsigned int* va = (unsigned int*)alloc((size_t)N_NODES * D * 4);
    float* ad     = (float*) alloc((size_t)N_NODES * D * 4);
    float* h0     = (float*) alloc((size_t)N_NODES * D * 4);
    float* h1     = (float*) alloc((size_t)N_NODES * D * 4);
    unsigned short* bpk = (unsigned short*)alloc((size_t)NLAYERS * LSTRIDE * 2);

    k_zero   <<<256,  256, 0, stream>>>(deg);
    k_hist   <<<4096, 256, 0, stream>>>(ei + N_EDGES, deg);
    k_scan1  <<<256,  256, 0, stream>>>(deg, part, bsum);
    k_scan2  <<<1,    256, 0, stream>>>(bsum, bofs);
    k_scan3  <<<256,  256, 0, stream>>>(part, bofs, off, cursor);
    k_scatter<<<4096, 256, 0, stream>>>(ei, pos, cursor, srcs, pdb);
    k_pack   <<<192,  256, 0, stream>>>(pW2, aW1, aW2, Wl, Ws, Wd, bpk);

    const float* hin = x;
    float* hbuf[2] = { h0, h1 };
    for (int L = 0; L < NLAYERS; ++L){
        float* hout = hbuf[L & 1];
        k_nodegemm<<<N_NODES/64, 256, 0, stream>>>(hin, bpk + (size_t)L*LSTRIDE,
            va, ad);
        k_edge<<<N_NODES/G, 256, 0, stream>>>(off, srcs, pdb, va, ad,
            pW1 + (size_t)L*2*D, pb1 + (size_t)L*D, pb2 + (size_t)L*D,
            ab1 + (size_t)L*D, ab2 + (size_t)L*D,
            bpk + (size_t)L*LSTRIDE,
            hout);
        hin = hout;
    }
    k_pool<<<NB, 256, 0, stream>>>(hin, outW, outb, out);
}

// Round 8
// 2271.849 us; speedup vs baseline: 1.1694x; 1.1694x over previous
//
#include <hip/hip_runtime.h>
#include <hip/hip_bf16.h>
#include <hip/hip_fp16.h>
#include <math.h>

#define N_NODES 65536
#define N_EDGES 1048576
#define NB      32
#define D       64
#define NLAYERS 4
#define G       16     // dst nodes per edge-block
#define CH      64     // edges per chunk
#define AST     76     // ushort stride, edge-kernel activation planes
#define PST     68     // ushort stride, p / M f16 planes
#define NST     72     // ushort stride, nodegemm planes
#define LOOFS   24576  // ushort offset of lo-plane in packed weights (per layer)
#define LSTRIDE 49152  // ushort stride per layer in packed weights

typedef __attribute__((ext_vector_type(8))) short short8;   // 8 bf16 in 4 VGPRs
typedef __attribute__((ext_vector_type(4))) float f32x4;

__device__ __forceinline__ float relu_f(float x){ return x > 0.f ? x : 0.f; }
__device__ __forceinline__ unsigned short bfbits(float x){
    __bf16 h = (__bf16)x;
    return __builtin_bit_cast(unsigned short, h);
}
__device__ __forceinline__ float bfval(float x){
    __bf16 h = (__bf16)x;
    return (float)h;
}
__device__ __forceinline__ f32x4 mfma16(short8 a, short8 b, f32x4 c){
    return __builtin_amdgcn_mfma_f32_16x16x32_bf16(a, b, c, 0, 0, 0);
}

// ---------------- sort-by-dst machinery ----------------

__global__ void k_zero(int* __restrict__ p){
    p[blockIdx.x * 256 + threadIdx.x] = 0;
}

__global__ void k_hist(const int* __restrict__ dst, int* __restrict__ deg){
    int e = blockIdx.x * 256 + threadIdx.x;
    if (e < N_EDGES) atomicAdd(&deg[dst[e]], 1);
}

__global__ void k_scan1(const int* __restrict__ deg, int* __restrict__ part, int* __restrict__ bsum){
    __shared__ int s[256];
    int t = threadIdx.x;
    int i = blockIdx.x * 256 + t;
    int v = deg[i];
    s[t] = v; __syncthreads();
    for (int ofs = 1; ofs < 256; ofs <<= 1){
        int tv = (t >= ofs) ? s[t - ofs] : 0;
        __syncthreads();
        s[t] += tv;
        __syncthreads();
    }
    part[i] = s[t] - v;
    if (t == 255) bsum[blockIdx.x] = s[255];
}

__global__ void k_scan2(const int* __restrict__ bsum, int* __restrict__ bofs){
    __shared__ int s[256];
    int t = threadIdx.x;
    int v = bsum[t];
    s[t] = v; __syncthreads();
    for (int ofs = 1; ofs < 256; ofs <<= 1){
        int tv = (t >= ofs) ? s[t - ofs] : 0;
        __syncthreads();
        s[t] += tv;
        __syncthreads();
    }
    bofs[t] = s[t] - v;
}

__global__ void k_scan3(const int* __restrict__ part, const int* __restrict__ bofs,
                        int* __restrict__ off, int* __restrict__ cursor){
    int i = blockIdx.x * 256 + threadIdx.x;
    int o = part[i] + bofs[i >> 8];
    off[i] = o; cursor[i] = o;
    if (i == 0) off[N_NODES] = N_EDGES;
}

__global__ void k_scatter(const int* __restrict__ ei, const float* __restrict__ pos,
                          int* __restrict__ cursor, int* __restrict__ srcs,
                          float* __restrict__ pdb){
    int e = blockIdx.x * 256 + threadIdx.x;
    if (e >= N_EDGES) return;
    int s = ei[e], d = ei[N_EDGES + e];
    int p = atomicAdd(&cursor[d], 1);
    srcs[p]    = s;
    pdb[2*p]   = pos[2*d]   - pos[2*s];
    pdb[2*p+1] = pos[2*d+1] - pos[2*s+1];
}

// ---------------- weight pre-pack into MFMA B-fragment order (hi/lo) ----------------
// 6 matrices per layer: 0..2 = pW2,aW1,aW2 (edge kernel), 3..5 = Wl,Ws,Wd (node GEMM).
// Per layer: hi plane 24576 ushorts at [mat][nb][kf][lane][8], lo plane at +LOOFS.
// B-frag: lane holds B[k = kf*32 + (lane>>4)*8 + j][n = nb*16 + (lane&15)], j=0..7.

__global__ void k_pack(const float* __restrict__ pW2, const float* __restrict__ aW1,
                       const float* __restrict__ aW2, const float* __restrict__ Wl,
                       const float* __restrict__ Ws, const float* __restrict__ Wd,
                       unsigned short* __restrict__ bpk){
    int b  = blockIdx.x;                // L*48 + mat*8 + nb*2 + kf
    int kf = b & 1, nb = (b >> 1) & 3;
    int mat = (b >> 3) % 6, L = b / 48;
    int t = threadIdx.x;
    int lane = t & 63, jj = (t >> 6) * 2;
    const float* Wsel[6] = {pW2, aW1, aW2, Wl, Ws, Wd};
    const float* W = Wsel[mat] + (size_t)L * D * D;
    int n = nb * 16 + (lane & 15);
    unsigned short* dsthi = bpk + (size_t)L * LSTRIDE
                          + (((size_t)mat * 4 + nb) * 2 + kf) * 512 + lane * 8 + jj;
    #pragma unroll
    for (int u = 0; u < 2; ++u){
        int j = jj + u;
        int k = kf * 32 + (lane >> 4) * 8 + j;
        float w = W[k * D + n];
        float hv = bfval(w);
        dsthi[u]         = bfbits(w);
        dsthi[LOOFS + u] = bfbits(w - hv);
    }
}

// ---------------- nodegemm helper: A hi/lo in LDS, persistent B frags ----------------

__device__ __forceinline__ void gemm_hl(const unsigned short* __restrict__ Ah,
                                        const unsigned short* __restrict__ Al,
                                        const short8* Bh, const short8* Bl,
                                        int ln, int q, f32x4* accs)
{
    #pragma unroll
    for (int mt = 0; mt < 4; ++mt){
        int ro = (mt*16 + ln) * NST;
        short8 ah0 = __builtin_bit_cast(short8, *(const uint4*)(Ah + ro + q*8));
        short8 ah1 = __builtin_bit_cast(short8, *(const uint4*)(Ah + ro + 32 + q*8));
        short8 al0 = __builtin_bit_cast(short8, *(const uint4*)(Al + ro + q*8));
        short8 al1 = __builtin_bit_cast(short8, *(const uint4*)(Al + ro + 32 + q*8));
        f32x4 acc = {0.f, 0.f, 0.f, 0.f};
        acc = mfma16(ah0, Bh[0], acc);
        acc = mfma16(ah1, Bh[1], acc);
        acc = mfma16(al0, Bh[0], acc);
        acc = mfma16(al1, Bh[1], acc);
        acc = mfma16(ah0, Bl[0], acc);
        acc = mfma16(ah1, Bl[1], acc);
        accs[mt] = acc;
    }
}

// ---------------- node GEMM (MFMA): va (packed half2 v|as) and ad (fp32) ----------------

__global__ __launch_bounds__(256, 4) void k_nodegemm(
    const float* __restrict__ h, const unsigned short* __restrict__ bpkL,
    unsigned int* __restrict__ VA, float* __restrict__ ad)
{
    __shared__ __align__(16) unsigned short Hhi[64 * NST];
    __shared__ __align__(16) unsigned short Hlo[64 * NST];
    int row0 = blockIdx.x * 64;
    int t = threadIdx.x;
    {
        int r  = t >> 2;
        int kb = (t & 3) * 16;
        const float4* hp = (const float4*)(h + (size_t)(row0 + r) * D + kb);
        unsigned int hw[8], lw[8];
        #pragma unroll
        for (int i4 = 0; i4 < 4; ++i4){
            float4 a = hp[i4];
            float f[4] = {a.x, a.y, a.z, a.w};
            #pragma unroll
            for (int p = 0; p < 2; ++p){
                float f0 = f[p*2], f1 = f[p*2+1];
                unsigned short h0 = bfbits(f0), h1 = bfbits(f1);
                unsigned short l0 = bfbits(f0 - bfval(f0)), l1 = bfbits(f1 - bfval(f1));
                hw[i4*2 + p] = (unsigned int)h0 | ((unsigned int)h1 << 16);
                lw[i4*2 + p] = (unsigned int)l0 | ((unsigned int)l1 << 16);
            }
        }
        *(uint4*)&Hhi[r*NST + kb]     = make_uint4(hw[0], hw[1], hw[2], hw[3]);
        *(uint4*)&Hhi[r*NST + kb + 8] = make_uint4(hw[4], hw[5], hw[6], hw[7]);
        *(uint4*)&Hlo[r*NST + kb]     = make_uint4(lw[0], lw[1], lw[2], lw[3]);
        *(uint4*)&Hlo[r*NST + kb + 8] = make_uint4(lw[4], lw[5], lw[6], lw[7]);
    }
    __syncthreads();
    int w = t >> 6, lane = t & 63;
    int q = lane >> 4, ln = lane & 15;
    int c = w * 16 + ln;
    short8 Bh[3][2], Bl[3][2];
    #pragma unroll
    for (int g = 0; g < 3; ++g)
        #pragma unroll
        for (int kf = 0; kf < 2; ++kf){
            int idx = (((g + 3)*4 + w)*2 + kf)*512 + lane*8;
            Bh[g][kf] = __builtin_bit_cast(short8, *(const uint4*)(bpkL + idx));
            Bl[g][kf] = __builtin_bit_cast(short8, *(const uint4*)(bpkL + LOOFS + idx));
        }
    f32x4 accs[4];
    float vres[16];
    gemm_hl(Hhi, Hlo, Bh[0], Bl[0], ln, q, accs);   // Wl -> v
    #pragma unroll
    for (int mt = 0; mt < 4; ++mt)
        #pragma unroll
        for (int r = 0; r < 4; ++r)
            vres[mt*4 + r] = accs[mt][r];
    gemm_hl(Hhi, Hlo, Bh[1], Bl[1], ln, q, accs);   // Ws -> as; pack (v, as) half2
    #pragma unroll
    for (int mt = 0; mt < 4; ++mt)
        #pragma unroll
        for (int r = 0; r < 4; ++r){
            __half2 pk = __halves2half2(__float2half(vres[mt*4 + r]), __float2half(accs[mt][r]));
            VA[(size_t)(row0 + mt*16 + q*4 + r) * D + c] = __builtin_bit_cast(unsigned int, pk);
        }
    gemm_hl(Hhi, Hlo, Bh[2], Bl[2], ln, q, accs);   // Wd -> ad (fp32)
    #pragma unroll
    for (int mt = 0; mt < 4; ++mt)
        #pragma unroll
        for (int r = 0; r < 4; ++r)
            ad[(size_t)(row0 + mt*16 + q*4 + r) * D + c] = accs[mt][r];
}

// ---------------- edge-kernel gemm: A single-plane bf16 LDS, B hi/lo from global ----------------

__device__ __forceinline__ void gemm1p(const unsigned short* __restrict__ A,
                                       const unsigned short* __restrict__ bgl,
                                       int ln, int q, f32x4* accs)
{
    short8 Bh0 = __builtin_bit_cast(short8, *(const uint4*)(bgl));
    short8 Bh1 = __builtin_bit_cast(short8, *(const uint4*)(bgl + 512));
    short8 Bl0 = __builtin_bit_cast(short8, *(const uint4*)(bgl + LOOFS));
    short8 Bl1 = __builtin_bit_cast(short8, *(const uint4*)(bgl + LOOFS + 512));
    #pragma unroll
    for (int mt = 0; mt < 4; ++mt){
        int ro = (mt*16 + ln) * AST;
        short8 a0 = __builtin_bit_cast(short8, *(const uint4*)(A + ro + q*8));
        short8 a1 = __builtin_bit_cast(short8, *(const uint4*)(A + ro + 32 + q*8));
        f32x4 acc = {0.f, 0.f, 0.f, 0.f};
        acc = mfma16(a0, Bh0, acc);
        acc = mfma16(a1, Bh1, acc);
        acc = mfma16(a0, Bl0, acc);
        acc = mfma16(a1, Bl1, acc);
        accs[mt] = acc;
    }
}

// ---------------- fused edge kernel: software-pipelined chunk loop ----------------
// Per-chunk barrier sections (4): [C: gemm1+epilogue] [D: gemm2] [E: gemm3->p]
// [F+AB': reduce chunk k; build t1/sp for k+1; ISSUE k+1's VA gathers].
// srcs/pdb for k+1 prefetched at top of C (hidden under C..E). VA gather results
// (vaq[16]) cross one barrier into C's epilogue. sp (1 reg/lane) re-broadcast via
// ds_bpermute in C for the ad (dst-local, L1-hot) loads.

__global__ __launch_bounds__(256, 4) void k_edge(
    const int* __restrict__ off, const int* __restrict__ srcs, const float* __restrict__ pdb,
    const unsigned int* __restrict__ VA, const float* __restrict__ adF,
    const float* __restrict__ pW1, const float* __restrict__ pb1, const float* __restrict__ pb2,
    const float* __restrict__ ab1, const float* __restrict__ ab2,
    const unsigned short* __restrict__ bpkL,
    float* __restrict__ hout)
{
    __shared__ __align__(16) unsigned short Tsh[64 * AST];   // 9728 B: t1 / t2
    __shared__ __align__(16) unsigned short Ush[64 * AST];   // 9728 B: u ; p f16 overlay (stride PST)
    __shared__ __align__(16) unsigned short Msh[64 * PST];   // 8704 B: M f16
    __shared__ int s_off[20];
    unsigned short* Ph = Ush;    // p f16 overlay, stride PST

    int t  = threadIdx.x;
    int n0 = blockIdx.x * G;
    if (t <= G) s_off[t] = off[n0 + t];
    __syncthreads();
    int e_begin = s_off[0], e_end = s_off[G];

    int w = t >> 6, lane = t & 63;
    int q = lane >> 4, ln = lane & 15;
    int c = w * 16 + ln;
    int kb = w * 16;                 // this wave's k-quarter for the pos-MLP

    const unsigned short* bg0 = bpkL + ((0*4 + w)*2)*512 + lane*8;
    const unsigned short* bg1 = bpkL + ((1*4 + w)*2)*512 + lane*8;
    const unsigned short* bg2 = bpkL + ((2*4 + w)*2)*512 + lane*8;

    float pb2c = pb2[c], ab1c = ab1[c], ab2c = ab2[c];

    float den[4] = {0.f, 0.f, 0.f, 0.f};
    float num[4] = {0.f, 0.f, 0.f, 0.f};

    int sp = 0;                      // this lane's (src | l<<16) for its chunk edge
    unsigned int vaq[16];            // prefetched VA gathers for current chunk

    // ---- AB-block for a chunk: sp, issue VA gathers, pos-MLP -> Tsh (no barrier inside)
    auto ab_block = [&](int ps, float p0, float p1, int ecN){
        int cntN = min(CH, e_end - ecN);
        int gg = ecN + ((lane < cntN) ? lane : 0);
        int l = 0;
        while (l < G-1 && gg >= s_off[l+1]) ++l;
        sp = (ps & 0xFFFF) | (l << 16);
        #pragma unroll
        for (int i = 0; i < 16; ++i){
            int e = (i >> 2)*16 + q*4 + (i & 3);
            int spe = __builtin_amdgcn_ds_bpermute(e << 2, sp);
            vaq[i] = VA[(size_t)(spe & 0xFFFF) * D + c];
        }
        unsigned int hw[8];
        #pragma unroll
        for (int i2 = 0; i2 < 8; ++i2){
            int k = kb + i2*2;
            float f0 = relu_f(fmaf(p1, pW1[D + k],     fmaf(p0, pW1[k],     pb1[k])));
            float f1 = relu_f(fmaf(p1, pW1[D + k + 1], fmaf(p0, pW1[k + 1], pb1[k + 1])));
            hw[i2] = (unsigned int)bfbits(f0) | ((unsigned int)bfbits(f1) << 16);
        }
        *(uint4*)&Tsh[lane*AST + kb]     = make_uint4(hw[0], hw[1], hw[2], hw[3]);
        *(uint4*)&Tsh[lane*AST + kb + 8] = make_uint4(hw[4], hw[5], hw[6], hw[7]);
    };

    // ---- prologue: chunk 0 metadata (blocking) + AB-block
    {
        int cnt0 = min(CH, e_end - e_begin);
        int gg = e_begin + ((lane < cnt0) ? lane : 0);
        int ps = srcs[gg];
        float p0 = pdb[2*gg], p1 = pdb[2*gg+1];
        ab_block(ps, p0, p1, e_begin);
    }
    __syncthreads();

    for (int ec = e_begin; ec < e_end; ec += CH){
        int cnt = min(CH, e_end - ec);
        int ecN = ec + CH;
        bool hasNext = ecN < e_end;
        // prefetch next chunk's metadata (clamped; consumed in F+AB')
        int gN;
        {
            int cntN = hasNext ? min(CH, e_end - ecN) : 1;
            int base = hasNext ? ecN : ec;
            gN = base + ((lane < cntN) ? lane : 0);
        }
        int   pf_s  = srcs[gN];
        float pf_p0 = pdb[2*gN], pf_p1 = pdb[2*gN+1];

        // ---- C: gemm1 (t1 @ pW2) -> delta; consume vaq; ad inline (L1-hot); M,u -> LDS
        {
            f32x4 accs[4];
            gemm1p(Tsh, bg0, ln, q, accs);
            #pragma unroll
            for (int mt = 0; mt < 4; ++mt){
                #pragma unroll
                for (int r = 0; r < 4; ++r){
                    int i = mt*4 + r;
                    int e = mt*16 + q*4 + r;
                    int spe = __builtin_amdgcn_ds_bpermute(e << 2, sp);
                    float adv = adF[(size_t)(n0 + (spe >> 16)) * D + c];
                    float dlt = relu_f(accs[mt][r] + pb2c);
                    __half2 va = __builtin_bit_cast(__half2, vaq[i]);
                    float vv = __low2float(va);
                    float vs = __high2float(va);
                    Msh[e*PST + c] = __builtin_bit_cast(unsigned short, __float2half(vv + dlt));
                    Ush[e*AST + c] = bfbits(adv - vs + dlt);
                }
            }
        }
        __syncthreads();
        // ---- D: gemm2 (u @ aW1) -> t2 -> T (overwrite t1)
        {
            f32x4 accs[4];
            gemm1p(Ush, bg1, ln, q, accs);
            #pragma unroll
            for (int mt = 0; mt < 4; ++mt)
                #pragma unroll
                for (int r = 0; r < 4; ++r){
                    int e = mt*16 + q*4 + r;
                    Tsh[e*AST + c] = bfbits(relu_f(accs[mt][r] + ab1c));
                }
        }
        __syncthreads();
        // ---- E: gemm3 (t2 @ aW2) -> alpha; p f16 -> U overlay (u dead after D)
        {
            f32x4 accs[4];
            gemm1p(Tsh, bg2, ln, q, accs);
            #pragma unroll
            for (int mt = 0; mt < 4; ++mt){
                #pragma unroll
                for (int r = 0; r < 4; ++r){
                    int e = mt*16 + q*4 + r;
                    float a = relu_f(accs[mt][r] + ab2c);
                    Ph[e*PST + c] = __builtin_bit_cast(unsigned short, __float2half(__expf(a)));
                }
            }
        }
        __syncthreads();
        // ---- F + AB': issue k+1 gathers early, build t1(k+1), then reduce chunk k
        if (hasNext)
            ab_block(pf_s, pf_p0, pf_p1, ecN);
        #pragma unroll
        for (int qn = 0; qn < 4; ++qn){
            int l  = w*4 + qn;
            int gs = max(s_off[l], ec);
            int ge = min(s_off[l+1], ec + cnt);
            float dd = den[qn], nn = num[qn];
            for (int g = gs; g < ge; ++g){
                int e = g - ec;
                float p = __half2float(__builtin_bit_cast(__half, Ph[e*PST + lane]));
                float m = __half2float(__builtin_bit_cast(__half, Msh[e*PST + lane]));
                dd += p;
                nn = fmaf(p, m, nn);
            }
            den[qn] = dd; num[qn] = nn;
        }
        __syncthreads();
    }
    #pragma unroll
    for (int qn = 0; qn < 4; ++qn){
        int n = n0 + w*4 + qn;
        hout[(size_t)n * D + lane] = num[qn] / den[qn];
    }
}

// ---------------- pooling + classifier ----------------

__global__ __launch_bounds__(256) void k_pool(const float* __restrict__ h,
                                              const float* __restrict__ outW,
                                              const float* __restrict__ outb,
                                              float* __restrict__ out)
{
    __shared__ float sm[4][64];
    __shared__ float sp[2][64];
    int b = blockIdx.x;
    int t = threadIdx.x, j = t & 63, g = t >> 6;
    float mx = -1e30f;
    for (int r = b*2048 + g; r < (b+1)*2048; r += 4)
        mx = fmaxf(mx, h[(size_t)r * D + j]);
    sm[g][j] = mx;
    __syncthreads();
    if (t < 64){
        float m = fmaxf(fmaxf(sm[0][j], sm[1][j]), fmaxf(sm[2][j], sm[3][j]));
        sp[0][j] = m * outW[j*2 + 0];
        sp[1][j] = m * outW[j*2 + 1];
    }
    __syncthreads();
    if (t == 0){
        float s0 = outb[0], s1 = outb[1];
        for (int k = 0; k < 64; ++k){ s0 += sp[0][k]; s1 += sp[1][k]; }
        out[b*2]   = s0;
        out[b*2+1] = s1;
    }
}

// ---------------- launch ----------------

extern "C" void kernel_launch(void* const* d_in, const int* in_sizes, int n_in,
                              void* d_out, int out_size, void* d_ws, size_t ws_size,
                              hipStream_t stream)
{
    const float* x    = (const float*)d_in[0];
    const float* pos  = (const float*)d_in[1];
    const float* Wl   = (const float*)d_in[2];
    const float* Ws   = (const float*)d_in[3];
    const float* Wd   = (const float*)d_in[4];
    const float* pW1  = (const float*)d_in[5];
    const float* pb1  = (const float*)d_in[6];
    const float* pW2  = (const float*)d_in[7];
    const float* pb2  = (const float*)d_in[8];
    const float* aW1  = (const float*)d_in[9];
    const float* ab1  = (const float*)d_in[10];
    const float* aW2  = (const float*)d_in[11];
    const float* ab2  = (const float*)d_in[12];
    const float* outW = (const float*)d_in[13];
    const float* outb = (const float*)d_in[14];
    const int*   ei   = (const int*)d_in[15];
    float* out = (float*)d_out;

    char* wp = (char*)d_ws;
    auto alloc = [&](size_t bytes){
        void* p = (void*)wp;
        wp += (bytes + 255) & ~(size_t)255;
        return p;
    };
    int*   deg    = (int*)  alloc((size_t)N_NODES * 4);
    int*   part   = (int*)  alloc((size_t)N_NODES * 4);
    int*   bsum   = (int*)  alloc(1024);
    int*   bofs   = (int*)  alloc(1024);
    int*   off    = (int*)  alloc((size_t)(N_NODES + 1) * 4);
    int*   cursor = (int*)  alloc((size_t)N_NODES * 4);
    int*   srcs   = (int*)  alloc((size_t)N_EDGES * 4);
    float* pdb    = (float*)alloc((size_t)N_EDGES * 8);
    unsigned int* va = (unsigned int*)alloc((size_t)N_NODES * D * 4);
    float* ad     = (float*) alloc((size_t)N_NODES * D * 4);
    float* h0     = (float*) alloc((size_t)N_NODES * D * 4);
    float* h1     = (float*) alloc((size_t)N_NODES * D * 4);
    unsigned short* bpk = (unsigned short*)alloc((size_t)NLAYERS * LSTRIDE * 2);

    k_zero   <<<256,  256, 0, stream>>>(deg);
    k_hist   <<<4096, 256, 0, stream>>>(ei + N_EDGES, deg);
    k_scan1  <<<256,  256, 0, stream>>>(deg, part, bsum);
    k_scan2  <<<1,    256, 0, stream>>>(bsum, bofs);
    k_scan3  <<<256,  256, 0, stream>>>(part, bofs, off, cursor);
    k_scatter<<<4096, 256, 0, stream>>>(ei, pos, cursor, srcs, pdb);
    k_pack   <<<192,  256, 0, stream>>>(pW2, aW1, aW2, Wl, Ws, Wd, bpk);

    const float* hin = x;
    float* hbuf[2] = { h0, h1 };
    for (int L = 0; L < NLAYERS; ++L){
        float* hout = hbuf[L & 1];
        k_nodegemm<<<N_NODES/64, 256, 0, stream>>>(hin, bpk + (size_t)L*LSTRIDE,
            va, ad);
        k_edge<<<N_NODES/G, 256, 0, stream>>>(off, srcs, pdb, va, ad,
            pW1 + (size_t)L*2*D, pb1 + (size_t)L*D, pb2 + (size_t)L*D,
            ab1 + (size_t)L*D, ab2 + (size_t)L*D,
            bpk + (size_t)L*LSTRIDE,
            hout);
        hin = hout;
    }
    k_pool<<<NB, 256, 0, stream>>>(hin, outW, outb, out);
}